// Round 9
// baseline (183.744 us; speedup 1.0000x reference)
//
#include <hip/hip_runtime.h>
#include <float.h>

// Problem constants (fixed by reference: B=8, D=64, H=64, W=64, K=8192)
constexpr int KCODES = 8192;
constexpr int DDIM   = 64;
constexpr int NTOK   = 32768;
constexpr int MT     = 32;                 // tokens per WG (2 sets x 16)
constexpr int KC     = 64;                 // codes per chunk
constexpr int NCH    = KCODES / KC;        // 128 chunks
constexpr int CBCHUNK = KC * DDIM * 2 * 2; // 16384 B (64 codes x 64 d x bf16 x {hi,lo})

typedef short v8s __attribute__((ext_vector_type(8)));
typedef float v4f __attribute__((ext_vector_type(4)));

static __device__ __forceinline__ unsigned short f2bf(float f) {
  union { float f; unsigned u; } v; v.f = f;
  return (unsigned short)((v.u + 0x7fffu + ((v.u >> 16) & 1u)) >> 16);  // RNE
}
static __device__ __forceinline__ float bf2f(unsigned short b) {
  union { unsigned u; float f; } v; v.u = (unsigned)b << 16;
  return v.f;
}

// ---- fused prep: bf16 hi/lo split, FRAGMENT-LINEAR for mfma_16x16x32_bf16
// A-operand (A[m=lane&15][k=(lane>>4)*8+j]), + biased half-norms
// hn[k] = 0.5*||c_k||^2 + 2.0 (bias keeps phase-1 scores positive -> fp32
// bit pattern monotone for the packed-key argmin; scores land in [~0.7,~4.5]).
__global__ __launch_bounds__(256) void prep_kernel(
    const float* __restrict__ cb, unsigned short* __restrict__ wcb,
    float* __restrict__ hn) {
  const int c = blockIdx.x;                 // chunk 0..127
  const int tid = threadIdx.x;
  const int g = tid >> 6, lane = tid & 63;
  const int quad = lane >> 4, col = lane & 15;
  const int code = c * KC + g * 16 + col;
  const float* src = cb + (size_t)code * DDIM;
  float sq = 0.f;
#pragma unroll
  for (int ks = 0; ks < 2; ++ks) {
    v8s hi, lo;
#pragma unroll
    for (int j = 0; j < 8; ++j) {
      const float x = src[ks * 32 + quad * 8 + j];
      sq += x * x;
      const unsigned short h = f2bf(x);
      const unsigned short l = f2bf(x - bf2f(h));   // residual (Sterbenz-exact sub)
      hi[j] = (short)h; lo[j] = (short)l;
    }
    const size_t b0 = ((size_t)c * CBCHUNK + g * 4096 + ks * 1024 + lane * 16) / 2;
    *reinterpret_cast<v8s*>(wcb + b0)        = hi;
    *reinterpret_cast<v8s*>(wcb + b0 + 1024) = lo;
  }
  sq += __shfl_xor(sq, 16);
  sq += __shfl_xor(sq, 32);
  if (quad == 0) hn[code] = 0.5f * sq + 2.0f;
}

// Phase 1: bf16-split MFMA (acc = hn - xh*ch - xh*cl - xl*ch, |err|<~2e-5),
//   A-frags register-double-buffered from global (coalesced dwordx4, no
//   k-loop barriers). MT=32/grid=1024 -> 4 WG/CU = 4 waves/SIMD: stalls
//   covered by co-resident waves. Branchless packed-key top-2 per
//   (lane,set) cell: key = (score-bits & ~511) | (it*4 + r); floor
//   quantization <= 512*ulp(score) <= 1.2e-4, absorbed by the 4e-4 margin.
// Phase 2: fast path when unique candidate within smin+4e-4 (proof: winner
//   true-score <= smin+1.4e-4; any other stored>lim has true-score >=
//   smin+3.8e-4 -> ordering safe even under numpy's ulp(64)~1.5e-5 noise;
//   a numpy-winner distinct from the approx winner would itself be within
//   lim -> cnt>=2 -> refine). Refine = numpy-fp32-faithful decision
//   (pairwise-8 sums, D=fl(fl(S-2p)+N), correctly-rounded-fp64 p,
//   tie -> lowest index) — identical to all passing rounds.
__global__ __launch_bounds__(256, 4) void vq_kernel(
    const float* __restrict__ ze, const float* __restrict__ cb,
    const float* __restrict__ hn, const unsigned short* __restrict__ wcb,
    float* __restrict__ out) {
  __shared__ float c_s1[16][MT];   // per-cell best (floored) score
  __shared__ float c_s2[16][MT];
  __shared__ int   c_i1[16][MT];
  __shared__ int   c_i2[16][MT];
  __shared__ int   widx[MT];

  const int tid = threadIdx.x, lane = tid & 63, wv = tid >> 6;
  const int col = lane & 15, quad = lane >> 4;
  const int t0 = blockIdx.x * MT;
  const int bb = t0 >> 12, hw0 = t0 & 4095;   // 4096 % 32 == 0: one batch per WG
  const float* zb = ze + (size_t)bb * (DDIM * 4096) + hw0;

  // ---- B-frags: 2 sets x 16 tokens, negated + bf16-split, in registers.
  // B[k=(lane>>4)*8+j][n=lane&15]; token = s*16 + col; d = ks*32 + quad*8 + j.
  v8s nxh[2][2], nxl[2][2];
#pragma unroll
  for (int s = 0; s < 2; ++s) {
    const int mtok = s * 16 + col;
#pragma unroll
    for (int ks = 0; ks < 2; ++ks) {
#pragma unroll
      for (int j = 0; j < 8; ++j) {
        const int d = ks * 32 + quad * 8 + j;
        const float x = -zb[(size_t)d * 4096 + mtok];
        const unsigned short h = f2bf(x);
        const unsigned short l = f2bf(x - bf2f(h));
        nxh[s][ks][j] = (short)h; nxl[s][ks][j] = (short)l;
      }
    }
  }

  // ---- A-frag register double buffer; each lane's 4 x 16B loads span the
  // wave's 4 x 1KB coalesced term-blocks {hi-ks0, hi-ks1, lo-ks0, lo-ks1}.
  const char* abase = (const char*)wcb + wv * 4096 + lane * 16;
  const float* hnp  = hn + wv * 16 + quad * 4;

  auto loadA = [&](v8s (&A)[4], v4f& hv, int it) {
    const char* p = abase + (size_t)it * CBCHUNK;
    A[0] = *reinterpret_cast<const v8s*>(p);
    A[1] = *reinterpret_cast<const v8s*>(p + 1024);
    A[2] = *reinterpret_cast<const v8s*>(p + 2048);
    A[3] = *reinterpret_cast<const v8s*>(p + 3072);
    hv = *reinterpret_cast<const v4f*>(hnp + (size_t)it * KC);
  };

  unsigned m1[2] = {0xFFFFFFFFu, 0xFFFFFFFFu};   // packed running top-2 keys
  unsigned m2[2] = {0xFFFFFFFFu, 0xFFFFFFFFu};

  auto compute = [&](const v8s (&A)[4], const v4f hv, int it) {
    v4f acc[2];
#pragma unroll
    for (int s = 0; s < 2; ++s) acc[s] = hv;
#pragma unroll
    for (int s = 0; s < 2; ++s)
      acc[s] = __builtin_amdgcn_mfma_f32_16x16x32_bf16(A[0], nxh[s][0], acc[s], 0, 0, 0);
#pragma unroll
    for (int s = 0; s < 2; ++s)
      acc[s] = __builtin_amdgcn_mfma_f32_16x16x32_bf16(A[1], nxh[s][1], acc[s], 0, 0, 0);
#pragma unroll
    for (int s = 0; s < 2; ++s)
      acc[s] = __builtin_amdgcn_mfma_f32_16x16x32_bf16(A[2], nxh[s][0], acc[s], 0, 0, 0);
#pragma unroll
    for (int s = 0; s < 2; ++s)
      acc[s] = __builtin_amdgcn_mfma_f32_16x16x32_bf16(A[3], nxh[s][1], acc[s], 0, 0, 0);
#pragma unroll
    for (int s = 0; s < 2; ++s)
      acc[s] = __builtin_amdgcn_mfma_f32_16x16x32_bf16(A[0], nxl[s][0], acc[s], 0, 0, 0);
#pragma unroll
    for (int s = 0; s < 2; ++s)
      acc[s] = __builtin_amdgcn_mfma_f32_16x16x32_bf16(A[1], nxl[s][1], acc[s], 0, 0, 0);

    const unsigned base9 = (unsigned)(it * 4);   // 9-bit cell-local index base
#pragma unroll
    for (int s = 0; s < 2; ++s) {
      unsigned k0 = (__float_as_uint(acc[s][0]) & ~511u) | (base9 + 0);
      unsigned k1 = (__float_as_uint(acc[s][1]) & ~511u) | (base9 + 1);
      unsigned k2 = (__float_as_uint(acc[s][2]) & ~511u) | (base9 + 2);
      unsigned k3 = (__float_as_uint(acc[s][3]) & ~511u) | (base9 + 3);
      const unsigned km = min(min(k0, k1), min(k2, k3));
      const unsigned old1 = m1[s];
      m1[s] = min(old1, km);
      m2[s] = min(m2[s], max(old1, km));   // branchless 2nd-best
    }
  };

  v8s A0[4], A1[4]; v4f h0, h1;
  loadA(A0, h0, 0); loadA(A1, h1, 1);

  for (int it = 0; it < NCH; it += 2) {
    compute(A0, h0, it);
    if (it + 2 < NCH) loadA(A0, h0, it + 2);
    compute(A1, h1, it + 1);
    if (it + 3 < NCH) loadA(A1, h1, it + 3);
  }

  // ---- surface per-cell top-2 (cell = wv*4+quad; 16 cells x 512 codes) ----
  {
    const int cell = wv * 4 + quad;
#pragma unroll
    for (int s = 0; s < 2; ++s) {
      const int m = s * 16 + col;
      const unsigned K1 = m1[s], K2 = m2[s];
      c_s1[cell][m] = __uint_as_float(K1 & ~511u);
      c_s2[cell][m] = __uint_as_float(K2 & ~511u);
      // decode: local = it*4 + r -> code = it*64 + wv*16 + quad*4 + r
      c_i1[cell][m] = (int)((K1 & 511u) >> 2) * KC + wv * 16 + quad * 4 + (int)(K1 & 3u);
      c_i2[cell][m] = (int)((K2 & 511u) >> 2) * KC + wv * 16 + quad * 4 + (int)(K2 & 3u);
    }
  }
  __syncthreads();

  // ---- phase 2: fast path or numpy-faithful refine ----
  if (tid < MT) {
#pragma clang fp contract(off)   // numpy: separate mul then add; no FMA
    const int m = tid;

    float smin = FLT_MAX; int fidx = 0x7fffffff;
    for (int c = 0; c < 16; ++c) {
      const float a = c_s1[c][m];
      if (a < smin) { smin = a; fidx = c_i1[c][m]; }
    }
    const float lim = smin + 4e-4f;   // covers key-floor 1.2e-4 + approx 2e-5
                                      // + numpy ulp(64) noise, with 2x slack
    int cnt = 0;
    for (int c = 0; c < 16; ++c) {
      cnt += (c_s1[c][m] <= lim);
      cnt += (c_s2[c][m] <= lim);
    }

    int besti;
    if (cnt == 1) {
      besti = fidx;   // unique in-margin candidate: approx argmin == numpy argmin
    } else {
      const float* xz = zb + m;
      float xm[DDIM];
      for (int d = 0; d < DDIM; ++d) xm[d] = xz[(size_t)d * 4096];

      float r[8];
      for (int j = 0; j < 8; ++j) r[j] = xm[j] * xm[j];
      for (int i = 8; i < DDIM; i += 8)
        for (int j = 0; j < 8; ++j) r[j] += xm[i + j] * xm[i + j];
      const float S = ((r[0] + r[1]) + (r[2] + r[3])) + ((r[4] + r[5]) + (r[6] + r[7]));

      float bestD = FLT_MAX;
      besti = 0x7fffffff;
      for (int c = 0; c < 16; ++c) {
        for (int h = 0; h < 2; ++h) {
          const float sp = h ? c_s2[c][m] : c_s1[c][m];
          if (sp > lim) continue;
          const int idx = h ? c_i2[c][m] : c_i1[c][m];
          const float* crow = cb + (size_t)idx * DDIM;

          float rn[8];
          for (int j = 0; j < 8; ++j) rn[j] = crow[j] * crow[j];
          for (int i = 8; i < DDIM; i += 8)
            for (int j = 0; j < 8; ++j) rn[j] += crow[i + j] * crow[i + j];
          const float Nk =
              ((rn[0] + rn[1]) + (rn[2] + rn[3])) + ((rn[4] + rn[5]) + (rn[6] + rn[7]));

          double p64 = 0.0;
          for (int d = 0; d < DDIM; ++d) p64 += (double)xm[d] * (double)crow[d];
          const float pf = (float)p64;

          const float twop = 2.0f * pf;
          const float t1   = S - twop;
          const float Dv   = t1 + Nk;
          if (Dv < bestD || (Dv == bestD && idx < besti)) { bestD = Dv; besti = idx; }
        }
      }
    }
    widx[m] = besti;
  }
  __syncthreads();

  // ---- gather winners, write z_q (32-lane coalesced rows; cb L2-hot) ----
  {
    const int m = tid & 31, dg = tid >> 5;    // dg 0..7
    const int wi = widx[m];
    const float* crow = cb + (size_t)wi * DDIM;
    float* ob = out + (size_t)bb * (DDIM * 4096) + hw0;
#pragma unroll
    for (int p = 0; p < 8; ++p) {
      const int d = dg * 8 + p;
      ob[(size_t)d * 4096 + m] = crow[d];
    }
  }
}

extern "C" void kernel_launch(void* const* d_in, const int* in_sizes, int n_in,
                              void* d_out, int out_size, void* d_ws, size_t ws_size,
                              hipStream_t stream) {
  const float* ze = (const float*)d_in[0];    // [8,64,64,64]
  const float* cb = (const float*)d_in[1];    // [8192,64]
  float* hn = (float*)d_ws;                                     // 32 KB
  unsigned short* wcb = (unsigned short*)((char*)d_ws + 32768); // 2 MB frag-linear split
  float* out = (float*)d_out;

  prep_kernel<<<NCH, 256, 0, stream>>>(cb, wcb, hn);
  vq_kernel<<<NTOK / MT, 256, 0, stream>>>(ze, cb, hn, wcb, out);
}

// Round 10
// 167.739 us; speedup vs baseline: 1.0954x; 1.0954x over previous
//
#include <hip/hip_runtime.h>
#include <float.h>

// Problem constants (fixed by reference: B=8, D=64, H=64, W=64, K=8192)
constexpr int KCODES = 8192;
constexpr int DDIM   = 64;
constexpr int NTOK   = 32768;
constexpr int MT     = 32;                 // tokens per WG (2 sets x 16)
constexpr int KC     = 64;                 // codes per chunk
constexpr int NCH    = KCODES / KC;        // 128 chunks
constexpr int CBCHUNK = KC * DDIM * 2;     // 8192 B (64 codes x 64 d x bf16, hi only)

typedef short v8s __attribute__((ext_vector_type(8)));
typedef float v4f __attribute__((ext_vector_type(4)));

static __device__ __forceinline__ unsigned short f2bf(float f) {
  union { float f; unsigned u; } v; v.f = f;
  return (unsigned short)((v.u + 0x7fffu + ((v.u >> 16) & 1u)) >> 16);  // RNE
}

// ---- fused prep: bf16 hi codebook, FRAGMENT-LINEAR for mfma_16x16x32_bf16
// A-operand (A[m=lane&15][k=(lane>>4)*8+j]), + biased half-norms
// hn[k] = 0.5*||c_k||^2 + 2.0 (bias keeps phase-1 scores positive -> fp32
// bit pattern monotone for the packed-key argmin; scores land in [~0.7,~4.5]).
// Per chunk c: byte off = c*8192 + g*2048 + ks*1024 + lane*16 + j*2.
__global__ __launch_bounds__(256) void prep_kernel(
    const float* __restrict__ cb, unsigned short* __restrict__ wcb,
    float* __restrict__ hn) {
  const int c = blockIdx.x;                 // chunk 0..127
  const int tid = threadIdx.x;
  const int g = tid >> 6, lane = tid & 63;
  const int quad = lane >> 4, col = lane & 15;
  const int code = c * KC + g * 16 + col;
  const float* src = cb + (size_t)code * DDIM;
  float sq = 0.f;
#pragma unroll
  for (int ks = 0; ks < 2; ++ks) {
    v8s hi;
#pragma unroll
    for (int j = 0; j < 8; ++j) {
      const float x = src[ks * 32 + quad * 8 + j];
      sq += x * x;
      hi[j] = (short)f2bf(x);
    }
    const size_t b0 = ((size_t)c * CBCHUNK + g * 2048 + ks * 1024 + lane * 16) / 2;
    *reinterpret_cast<v8s*>(wcb + b0) = hi;
  }
  sq += __shfl_xor(sq, 16);
  sq += __shfl_xor(sq, 32);
  if (quad == 0) hn[code] = 0.5f * sq + 2.0f;
}

// Phase 1 (SCREEN): hi-only bf16 MFMA, score ~= hn - xh.ch.
//   Screening error e = xl.c + xh.cl: RMS ~2.5e-4, |e| <= ~2.8e-3 at 11
//   sigma. A-frags register-double-buffered from global (coalesced dwordx4,
//   no k-loop barriers); 4 WG/CU. Branchless packed-key top-2 per
//   (lane,set) cell: key = (score-bits & ~511) | (it*4 + r); floor
//   quantization <= 512 ulp <= 2.4e-4.
// Phase 2: fast path when unique candidate within smin+8e-3. Proof: for any
//   candidate with stored > lim: true > stored - e > smin + 8e-3 - 2.8e-3;
//   smin >= true_min - e - 2.4e-4 -> true - true_min > 8e-3 - 5.6e-3 -
//   2.4e-4 > 2e-3 >> numpy's ulp(64) ~1.5e-5 quantization -> numpy cannot
//   prefer it. A numpy-winner distinct from the approx winner is itself
//   within lim -> cnt >= 2 -> refine. Refine = numpy-fp32-faithful decision
//   (pairwise-8 sums, D=fl(fl(S-2p)+N), correctly-rounded-fp64 p,
//   tie -> lowest index) — identical to all passing rounds.
__global__ __launch_bounds__(256, 4) void vq_kernel(
    const float* __restrict__ ze, const float* __restrict__ cb,
    const float* __restrict__ hn, const unsigned short* __restrict__ wcb,
    float* __restrict__ out) {
  __shared__ float c_s1[16][MT];   // per-cell best (floored) score
  __shared__ float c_s2[16][MT];
  __shared__ int   c_i1[16][MT];
  __shared__ int   c_i2[16][MT];
  __shared__ int   widx[MT];

  const int tid = threadIdx.x, lane = tid & 63, wv = tid >> 6;
  const int col = lane & 15, quad = lane >> 4;
  const int t0 = blockIdx.x * MT;
  const int bb = t0 >> 12, hw0 = t0 & 4095;   // 4096 % 32 == 0: one batch per WG
  const float* zb = ze + (size_t)bb * (DDIM * 4096) + hw0;

  // ---- B-frags: 2 sets x 16 tokens, negated bf16-hi, in registers.
  // B[k=(lane>>4)*8+j][n=lane&15]; token = s*16 + col; d = ks*32 + quad*8 + j.
  v8s nxh[2][2];
#pragma unroll
  for (int s = 0; s < 2; ++s) {
    const int mtok = s * 16 + col;
#pragma unroll
    for (int ks = 0; ks < 2; ++ks) {
#pragma unroll
      for (int j = 0; j < 8; ++j) {
        const int d = ks * 32 + quad * 8 + j;
        nxh[s][ks][j] = (short)f2bf(-zb[(size_t)d * 4096 + mtok]);
      }
    }
  }

  // ---- A-frag register double buffer; each lane's 2 x 16B loads span the
  // wave's 2 x 1KB coalesced term-blocks {hi-ks0, hi-ks1}.
  const char* abase = (const char*)wcb + wv * 2048 + lane * 16;
  const float* hnp  = hn + wv * 16 + quad * 4;

  auto loadA = [&](v8s (&A)[2], v4f& hv, int it) {
    const char* p = abase + (size_t)it * CBCHUNK;
    A[0] = *reinterpret_cast<const v8s*>(p);
    A[1] = *reinterpret_cast<const v8s*>(p + 1024);
    hv = *reinterpret_cast<const v4f*>(hnp + (size_t)it * KC);
  };

  unsigned m1[2] = {0xFFFFFFFFu, 0xFFFFFFFFu};   // packed running top-2 keys
  unsigned m2[2] = {0xFFFFFFFFu, 0xFFFFFFFFu};

  auto compute = [&](const v8s (&A)[2], const v4f hv, int it) {
    v4f acc[2];
#pragma unroll
    for (int s = 0; s < 2; ++s) acc[s] = hv;
#pragma unroll
    for (int s = 0; s < 2; ++s)
      acc[s] = __builtin_amdgcn_mfma_f32_16x16x32_bf16(A[0], nxh[s][0], acc[s], 0, 0, 0);
#pragma unroll
    for (int s = 0; s < 2; ++s)
      acc[s] = __builtin_amdgcn_mfma_f32_16x16x32_bf16(A[1], nxh[s][1], acc[s], 0, 0, 0);

    const unsigned base9 = (unsigned)(it * 4);   // 9-bit cell-local index base
#pragma unroll
    for (int s = 0; s < 2; ++s) {
      unsigned k0 = (__float_as_uint(acc[s][0]) & ~511u) | (base9 + 0);
      unsigned k1 = (__float_as_uint(acc[s][1]) & ~511u) | (base9 + 1);
      unsigned k2 = (__float_as_uint(acc[s][2]) & ~511u) | (base9 + 2);
      unsigned k3 = (__float_as_uint(acc[s][3]) & ~511u) | (base9 + 3);
      const unsigned km = min(min(k0, k1), min(k2, k3));
      const unsigned old1 = m1[s];
      m1[s] = min(old1, km);
      m2[s] = min(m2[s], max(old1, km));   // branchless 2nd-best
    }
  };

  v8s A0[2], A1[2]; v4f h0, h1;
  loadA(A0, h0, 0); loadA(A1, h1, 1);

  for (int it = 0; it < NCH; it += 2) {
    compute(A0, h0, it);
    if (it + 2 < NCH) loadA(A0, h0, it + 2);
    compute(A1, h1, it + 1);
    if (it + 3 < NCH) loadA(A1, h1, it + 3);
  }

  // ---- surface per-cell top-2 (cell = wv*4+quad; 16 cells x 512 codes) ----
  {
    const int cell = wv * 4 + quad;
#pragma unroll
    for (int s = 0; s < 2; ++s) {
      const int m = s * 16 + col;
      const unsigned K1 = m1[s], K2 = m2[s];
      c_s1[cell][m] = __uint_as_float(K1 & ~511u);
      c_s2[cell][m] = __uint_as_float(K2 & ~511u);
      // decode: local = it*4 + r -> code = it*64 + wv*16 + quad*4 + r
      c_i1[cell][m] = (int)((K1 & 511u) >> 2) * KC + wv * 16 + quad * 4 + (int)(K1 & 3u);
      c_i2[cell][m] = (int)((K2 & 511u) >> 2) * KC + wv * 16 + quad * 4 + (int)(K2 & 3u);
    }
  }
  __syncthreads();

  // ---- phase 2: fast path or numpy-faithful refine ----
  if (tid < MT) {
#pragma clang fp contract(off)   // numpy: separate mul then add; no FMA
    const int m = tid;

    float smin = FLT_MAX; int fidx = 0x7fffffff;
    for (int c = 0; c < 16; ++c) {
      const float a = c_s1[c][m];
      if (a < smin) { smin = a; fidx = c_i1[c][m]; }
    }
    const float lim = smin + 8e-3f;   // covers 2*e_screen(2.8e-3) + key floor
                                      // 2.4e-4 + numpy noise, ~1.4x slack
    int cnt = 0;
    for (int c = 0; c < 16; ++c) {
      cnt += (c_s1[c][m] <= lim);
      cnt += (c_s2[c][m] <= lim);
    }

    int besti;
    if (cnt == 1) {
      besti = fidx;   // unique in-margin candidate: approx argmin == numpy argmin
    } else {
      const float* xz = zb + m;
      float xm[DDIM];
      for (int d = 0; d < DDIM; ++d) xm[d] = xz[(size_t)d * 4096];

      float r[8];
      for (int j = 0; j < 8; ++j) r[j] = xm[j] * xm[j];
      for (int i = 8; i < DDIM; i += 8)
        for (int j = 0; j < 8; ++j) r[j] += xm[i + j] * xm[i + j];
      const float S = ((r[0] + r[1]) + (r[2] + r[3])) + ((r[4] + r[5]) + (r[6] + r[7]));

      float bestD = FLT_MAX;
      besti = 0x7fffffff;
      for (int c = 0; c < 16; ++c) {
        for (int h = 0; h < 2; ++h) {
          const float sp = h ? c_s2[c][m] : c_s1[c][m];
          if (sp > lim) continue;
          const int idx = h ? c_i2[c][m] : c_i1[c][m];
          const float* crow = cb + (size_t)idx * DDIM;

          float rn[8];
          for (int j = 0; j < 8; ++j) rn[j] = crow[j] * crow[j];
          for (int i = 8; i < DDIM; i += 8)
            for (int j = 0; j < 8; ++j) rn[j] += crow[i + j] * crow[i + j];
          const float Nk =
              ((rn[0] + rn[1]) + (rn[2] + rn[3])) + ((rn[4] + rn[5]) + (rn[6] + rn[7]));

          double p64 = 0.0;
          for (int d = 0; d < DDIM; ++d) p64 += (double)xm[d] * (double)crow[d];
          const float pf = (float)p64;

          const float twop = 2.0f * pf;
          const float t1   = S - twop;
          const float Dv   = t1 + Nk;
          if (Dv < bestD || (Dv == bestD && idx < besti)) { bestD = Dv; besti = idx; }
        }
      }
    }
    widx[m] = besti;
  }
  __syncthreads();

  // ---- gather winners, write z_q (32-lane coalesced rows; cb L2-hot) ----
  {
    const int m = tid & 31, dg = tid >> 5;    // dg 0..7
    const int wi = widx[m];
    const float* crow = cb + (size_t)wi * DDIM;
    float* ob = out + (size_t)bb * (DDIM * 4096) + hw0;
#pragma unroll
    for (int p = 0; p < 8; ++p) {
      const int d = dg * 8 + p;
      ob[(size_t)d * 4096 + m] = crow[d];
    }
  }
}

extern "C" void kernel_launch(void* const* d_in, const int* in_sizes, int n_in,
                              void* d_out, int out_size, void* d_ws, size_t ws_size,
                              hipStream_t stream) {
  const float* ze = (const float*)d_in[0];    // [8,64,64,64]
  const float* cb = (const float*)d_in[1];    // [8192,64]
  float* hn = (float*)d_ws;                                     // 32 KB
  unsigned short* wcb = (unsigned short*)((char*)d_ws + 32768); // 1 MB frag-linear hi
  float* out = (float*)d_out;

  prep_kernel<<<NCH, 256, 0, stream>>>(cb, wcb, hn);
  vq_kernel<<<NTOK / MT, 256, 0, stream>>>(ze, cb, hn, wcb, out);
}